// Round 1
// baseline (262.205 us; speedup 1.0000x reference)
//
#include <hip/hip_runtime.h>
#include <hip/hip_bf16.h>

#define B_ 8
#define T_ 2048
#define C_ 1024
#define H_ 64

typedef __bf16 bf16x8 __attribute__((ext_vector_type(8)));
typedef float f32x4 __attribute__((ext_vector_type(4)));

// ---------------- Kernel 0: weight transpose + bf16 cast ----------------
// Wt[m][h][c] = W_m[c][h] (* 1/32 for m==0, folding in scale = C^-0.5)
__global__ __launch_bounds__(256) void prep_w_k(const float* __restrict__ Wq,
                                                const float* __restrict__ Wk,
                                                const float* __restrict__ Wv,
                                                __bf16* __restrict__ Wt) {
  int idx = blockIdx.x * 256 + threadIdx.x;  // 49152 total (3*64*256)
  int m = idx >> 14;
  int rem = idx & 16383;
  int h = rem >> 8;
  int c4 = (rem & 255) << 2;
  const float* W = (m == 0) ? Wq : ((m == 1) ? Wk : Wv);
  float sc = (m == 0) ? 0.03125f : 1.0f;
  __bf16* dst = Wt + ((size_t)(m * H_ + h)) * C_ + c4;
#pragma unroll
  for (int i = 0; i < 4; ++i) dst[i] = (__bf16)(W[(size_t)(c4 + i) * H_ + h] * sc);
}

// ---------------- Kernel 1: fused QKV projection (MFMA) ----------------
// q,k: [B*T][64] bf16 ; v: transposed to vt[b][h][t] bf16 via LDS tile
__global__ __launch_bounds__(256) void qkv_k(const float* __restrict__ x,
                                             const __bf16* __restrict__ Wt,
                                             __bf16* __restrict__ q,
                                             __bf16* __restrict__ k,
                                             __bf16* __restrict__ vt) {
  __shared__ __align__(16) char vtile[64 * 64 * 2];  // [h][t_local] swizzled
  const int tid = threadIdx.x;
  const int lane = tid & 63;
  const int w = tid >> 6;
  const int l15 = lane & 15;
  const int g = lane >> 4;
  const int row0 = blockIdx.x * 64 + w * 16;

  f32x4 acc[12];
#pragma unroll
  for (int i = 0; i < 12; ++i) acc[i] = (f32x4)0.0f;

  const float* xp = x + (size_t)(row0 + l15) * C_ + g * 8;
  for (int kb = 0; kb < 32; ++kb) {
    float4 a0 = *(const float4*)(xp + kb * 32);
    float4 a1 = *(const float4*)(xp + kb * 32 + 4);
    bf16x8 af;
    af[0] = (__bf16)a0.x; af[1] = (__bf16)a0.y; af[2] = (__bf16)a0.z; af[3] = (__bf16)a0.w;
    af[4] = (__bf16)a1.x; af[5] = (__bf16)a1.y; af[6] = (__bf16)a1.z; af[7] = (__bf16)a1.w;
#pragma unroll
    for (int ct = 0; ct < 12; ++ct) {
      int m = ct >> 2;
      int col = ((ct & 3) << 4) + l15;
      const bf16x8* bp = (const bf16x8*)(Wt + (size_t)(m * 64 + col) * C_ + kb * 32 + g * 8);
      acc[ct] = __builtin_amdgcn_mfma_f32_16x16x32_bf16(af, *bp, acc[ct], 0, 0, 0);
    }
  }

  // q, k epilogue: D frag (row = g*4+r, col = ct*16+l15)
  const int drow = row0 + g * 4;
#pragma unroll
  for (int ct = 0; ct < 4; ++ct) {
#pragma unroll
    for (int r = 0; r < 4; ++r) {
      q[(size_t)(drow + r) * H_ + ct * 16 + l15] = (__bf16)acc[ct][r];
      k[(size_t)(drow + r) * H_ + ct * 16 + l15] = (__bf16)acc[4 + ct][r];
    }
  }

  // v epilogue: transpose through LDS → vt[b][h][t]
  const int tl = w * 16 + g * 4;
#pragma unroll
  for (int ct = 0; ct < 4; ++ct) {
    int hh = ct * 16 + l15;
#pragma unroll
    for (int r = 0; r < 4; ++r) {
      int off = ((hh * 64 + tl + r) * 2) ^ ((hh & 7) << 4);
      *(__bf16*)(vtile + off) = (__bf16)acc[8 + ct][r];
    }
  }
  __syncthreads();
  const int h = tid >> 2;
  const int t0 = (tid & 3) * 16;
  int o0 = ((h * 64 + t0) * 2) ^ ((h & 7) << 4);
  int o1 = ((h * 64 + t0 + 8) * 2) ^ ((h & 7) << 4);
  bf16x8 v0 = *(const bf16x8*)(vtile + o0);
  bf16x8 v1 = *(const bf16x8*)(vtile + o1);
  int bb = blockIdx.x >> 5;
  int tglob = (blockIdx.x & 31) * 64 + t0;
  __bf16* dst = vt + ((size_t)bb * 64 + h) * T_ + tglob;
  *(bf16x8*)dst = v0;
  *(bf16x8*)(dst + 8) = v1;
}

// ---------------- Kernel 2: causal flash attention ----------------
// grid = (b, qb): 8*32 blocks; 4 waves x 16 q-rows; KVBLK=64
__global__ __launch_bounds__(256) void attn_k(const __bf16* __restrict__ q,
                                              const __bf16* __restrict__ k,
                                              const __bf16* __restrict__ vt,
                                              float* __restrict__ out) {
  __shared__ __align__(16) char plds[4 * 16 * 64 * 2];  // per-wave P tile [q][kv] swizzled
  const int tid = threadIdx.x;
  const int lane = tid & 63;
  const int w = tid >> 6;
  const int l15 = lane & 15;
  const int g = lane >> 4;
  const int b = blockIdx.x >> 5;
  const int qb = blockIdx.x & 31;
  const size_t qkbase = (size_t)b * T_ * H_;
  const int qr0 = qb * 64 + w * 16;

  const __bf16* qp = q + qkbase + (size_t)(qr0 + l15) * H_ + g * 8;
  bf16x8 aq0 = *(const bf16x8*)qp;
  bf16x8 aq1 = *(const bf16x8*)(qp + 32);

  f32x4 accO[4];
#pragma unroll
  for (int i = 0; i < 4; ++i) accO[i] = (f32x4)0.0f;
  float mrow[4] = {-1e30f, -1e30f, -1e30f, -1e30f};
  float lsum[4] = {0.f, 0.f, 0.f, 0.f};
  char* pb = plds + w * 2048;
  const __bf16* vb = vt + (size_t)b * 64 * T_;

  for (int kb = 0; kb <= qb; ++kb) {
    const int kvb = kb * 64;
    // S = Q K^T (scale pre-folded into q)
    f32x4 s[4];
#pragma unroll
    for (int ct = 0; ct < 4; ++ct) {
      const __bf16* kp = k + qkbase + (size_t)(kvb + ct * 16 + l15) * H_ + g * 8;
      bf16x8 b0 = *(const bf16x8*)kp;
      bf16x8 b1 = *(const bf16x8*)(kp + 32);
      f32x4 z = (f32x4)0.0f;
      z = __builtin_amdgcn_mfma_f32_16x16x32_bf16(aq0, b0, z, 0, 0, 0);
      z = __builtin_amdgcn_mfma_f32_16x16x32_bf16(aq1, b1, z, 0, 0, 0);
      s[ct] = z;
    }
    if (kb == qb) {  // causal mask on diagonal block
#pragma unroll
      for (int ct = 0; ct < 4; ++ct)
#pragma unroll
        for (int r = 0; r < 4; ++r)
          if (kvb + ct * 16 + l15 > qr0 + g * 4 + r) s[ct][r] = -1e30f;
    }
    // wave-parallel online softmax (row r lives in a 16-lane group, reg r&3)
    float al[4];
#pragma unroll
    for (int r = 0; r < 4; ++r) {
      float v = fmaxf(fmaxf(s[0][r], s[1][r]), fmaxf(s[2][r], s[3][r]));
      v = fmaxf(v, __shfl_xor(v, 1, 64));
      v = fmaxf(v, __shfl_xor(v, 2, 64));
      v = fmaxf(v, __shfl_xor(v, 4, 64));
      v = fmaxf(v, __shfl_xor(v, 8, 64));
      float m2 = fmaxf(mrow[r], v);
      al[r] = __expf(mrow[r] - m2);
      mrow[r] = m2;
    }
#pragma unroll
    for (int ct = 0; ct < 4; ++ct)
#pragma unroll
      for (int r = 0; r < 4; ++r) s[ct][r] = __expf(s[ct][r] - mrow[r]);
#pragma unroll
    for (int r = 0; r < 4; ++r) {
      lsum[r] = lsum[r] * al[r] + (s[0][r] + s[1][r]) + (s[2][r] + s[3][r]);
#pragma unroll
      for (int hct = 0; hct < 4; ++hct) accO[hct][r] *= al[r];
    }
    // P → LDS [q][kv] (swizzled), then read back as A-fragments
#pragma unroll
    for (int ct = 0; ct < 4; ++ct)
#pragma unroll
      for (int r = 0; r < 4; ++r) {
        int qrow = g * 4 + r;
        int off = ((qrow * 64 + ct * 16 + l15) * 2) ^ ((qrow & 7) << 4);
        *(__bf16*)(pb + off) = (__bf16)s[ct][r];
      }
#pragma unroll
    for (int ks = 0; ks < 2; ++ks) {
      int off = ((l15 * 64 + ks * 32 + g * 8) * 2) ^ ((l15 & 7) << 4);
      bf16x8 pa = *(const bf16x8*)(pb + off);
#pragma unroll
      for (int hct = 0; hct < 4; ++hct) {
        const __bf16* vp = vb + (size_t)(hct * 16 + l15) * T_ + kvb + ks * 32 + g * 8;
        bf16x8 bv = *(const bf16x8*)vp;
        accO[hct] = __builtin_amdgcn_mfma_f32_16x16x32_bf16(pa, bv, accO[hct], 0, 0, 0);
      }
    }
  }
  // final: reduce lsum across 16-lane group, normalize, store f32
#pragma unroll
  for (int r = 0; r < 4; ++r) {
    float v = lsum[r];
    v += __shfl_xor(v, 1, 64);
    v += __shfl_xor(v, 2, 64);
    v += __shfl_xor(v, 4, 64);
    v += __shfl_xor(v, 8, 64);
    lsum[r] = 1.0f / v;
  }
  float* op = out + ((size_t)b * T_ + qr0) * H_;
#pragma unroll
  for (int hct = 0; hct < 4; ++hct)
#pragma unroll
    for (int r = 0; r < 4; ++r)
      op[(size_t)(g * 4 + r) * H_ + hct * 16 + l15] = accO[hct][r] * lsum[r];
}

// ---------------- launcher ----------------
extern "C" void kernel_launch(void* const* d_in, const int* in_sizes, int n_in,
                              void* d_out, int out_size, void* d_ws, size_t ws_size,
                              hipStream_t stream) {
  const float* x  = (const float*)d_in[0];
  const float* Wq = (const float*)d_in[1];
  const float* Wk = (const float*)d_in[2];
  const float* Wv = (const float*)d_in[3];
  float* out = (float*)d_out;
  char* ws = (char*)d_ws;
  __bf16* Wt  = (__bf16*)ws;                   // 3*64*1024*2 = 393216 B
  __bf16* qb  = (__bf16*)(ws + 0x60000);       // 2 MiB
  __bf16* kb  = (__bf16*)(ws + 0x260000);      // 2 MiB
  __bf16* vtb = (__bf16*)(ws + 0x460000);      // 2 MiB (vt[b][h][t])

  hipLaunchKernelGGL(prep_w_k, dim3(192), dim3(256), 0, stream, Wq, Wk, Wv, Wt);
  hipLaunchKernelGGL(qkv_k, dim3(256), dim3(256), 0, stream, x, Wt, qb, kb, vtb);
  hipLaunchKernelGGL(attn_k, dim3(256), dim3(256), 0, stream, qb, kb, vtb, out);
}

// Round 2
// 222.561 us; speedup vs baseline: 1.1781x; 1.1781x over previous
//
#include <hip/hip_runtime.h>
#include <hip/hip_bf16.h>

#define B_ 8
#define T_ 2048
#define C_ 1024
#define H_ 64

typedef __bf16 bf16x8 __attribute__((ext_vector_type(8)));
typedef float f32x4 __attribute__((ext_vector_type(4)));

// ---------------- Kernel 0: weight transpose + bf16 cast ----------------
// Wt[m][h][c] = W_m[c][h] (* 1/32 for m==0, folding in scale = C^-0.5)
__global__ __launch_bounds__(256) void prep_w_k(const float* __restrict__ Wq,
                                                const float* __restrict__ Wk,
                                                const float* __restrict__ Wv,
                                                __bf16* __restrict__ Wt) {
  int idx = blockIdx.x * 256 + threadIdx.x;  // 49152 total (3*64*256)
  int m = idx >> 14;
  int rem = idx & 16383;
  int h = rem >> 8;
  int c4 = (rem & 255) << 2;
  const float* W = (m == 0) ? Wq : ((m == 1) ? Wk : Wv);
  float sc = (m == 0) ? 0.03125f : 1.0f;
  __bf16* dst = Wt + ((size_t)(m * H_ + h)) * C_ + c4;
#pragma unroll
  for (int i = 0; i < 4; ++i) dst[i] = (__bf16)(W[(size_t)(c4 + i) * H_ + h] * sc);
}

// ---------------- Kernel 1: fused QKV projection (MFMA) ----------------
// 512 blocks x 512 threads; 8 waves: (w&1)=row-half (16 rows), (w>>1)=col-quarter (3 tiles)
// q,k: [B*T][64] bf16 ; v: transposed to vt[b][h][t] bf16 via LDS tile
__global__ __launch_bounds__(512) void qkv_k(const float* __restrict__ x,
                                             const __bf16* __restrict__ Wt,
                                             __bf16* __restrict__ q,
                                             __bf16* __restrict__ k,
                                             __bf16* __restrict__ vt) {
  __shared__ __align__(16) char vtile[64 * 32 * 2];  // [h][t_local 32] swizzled
  const int tid = threadIdx.x;
  const int lane = tid & 63;
  const int w = tid >> 6;        // 0..7
  const int l15 = lane & 15;
  const int g = lane >> 4;
  const int quarter = w >> 1;    // 0..3
  const int r0 = blockIdx.x * 32 + (w & 1) * 16;
  const int tcb = quarter * 3;   // base tile index (of 12)

  f32x4 acc[3];
#pragma unroll
  for (int i = 0; i < 3; ++i) acc[i] = (f32x4)0.0f;

  const float* xp = x + (size_t)(r0 + l15) * C_ + g * 8;
  for (int kb = 0; kb < 32; ++kb) {
    float4 a0 = *(const float4*)(xp + kb * 32);
    float4 a1 = *(const float4*)(xp + kb * 32 + 4);
    bf16x8 af;
    af[0] = (__bf16)a0.x; af[1] = (__bf16)a0.y; af[2] = (__bf16)a0.z; af[3] = (__bf16)a0.w;
    af[4] = (__bf16)a1.x; af[5] = (__bf16)a1.y; af[6] = (__bf16)a1.z; af[7] = (__bf16)a1.w;
#pragma unroll
    for (int ct = 0; ct < 3; ++ct) {
      int tc = tcb + ct;
      int m = tc >> 2;
      int col = ((tc & 3) << 4) + l15;
      const bf16x8* bp = (const bf16x8*)(Wt + (size_t)(m * 64 + col) * C_ + kb * 32 + g * 8);
      acc[ct] = __builtin_amdgcn_mfma_f32_16x16x32_bf16(af, *bp, acc[ct], 0, 0, 0);
    }
  }

  const int drow = r0 + g * 4;
#pragma unroll
  for (int ct = 0; ct < 3; ++ct) {
    int tc = tcb + ct;
    int m = tc >> 2;
    int hcol = ((tc & 3) << 4) + l15;
    if (m == 0) {
#pragma unroll
      for (int r = 0; r < 4; ++r)
        q[(size_t)(drow + r) * H_ + hcol] = (__bf16)acc[ct][r];
    } else if (m == 1) {
#pragma unroll
      for (int r = 0; r < 4; ++r)
        k[(size_t)(drow + r) * H_ + hcol] = (__bf16)acc[ct][r];
    } else {
      // v: write 4 t-consecutive bf16 as one 8B store into swizzled LDS tile
      int tl = (w & 1) * 16 + g * 4;
      union { ushort4 u; __bf16 h[4]; } pk;
#pragma unroll
      for (int r = 0; r < 4; ++r) pk.h[r] = (__bf16)acc[ct][r];
      int off = ((hcol * 32 + tl) * 2) ^ ((hcol & 7) << 4);
      *(ushort4*)(vtile + off) = pk.u;
    }
  }
  __syncthreads();
  // write out vt[b][h][t]: 512 threads cover 64h x 32t / 4
  const int h = tid >> 3;
  const int t4 = (tid & 7) * 4;
  int off = ((h * 32 + t4) * 2) ^ ((h & 7) << 4);
  unsigned long long v = *(const unsigned long long*)(vtile + off);
  int bb = blockIdx.x >> 6;
  int tglob = (blockIdx.x & 63) * 32 + t4;
  *(unsigned long long*)(vt + ((size_t)bb * 64 + h) * T_ + tglob) = v;
}

// ---------------- Kernel 2: causal flash attention, split-KV x4 ----------------
// grid = b(8) x qb(32) x piece(4); 4 waves x 16 q-rows; KVBLK=64
// writes unnormalized O partials + (m,l) per row
__global__ __launch_bounds__(256) void attn_k(const __bf16* __restrict__ q,
                                              const __bf16* __restrict__ k,
                                              const __bf16* __restrict__ vt,
                                              float* __restrict__ Opart,
                                              float2* __restrict__ ml) {
  __shared__ __align__(16) char plds[4 * 16 * 64 * 2];  // per-wave P tile [q][kv] swizzled
  const int bid = blockIdx.x;
  const int p = bid & 3;
  const int qb = (bid >> 2) & 31;
  const int b = bid >> 7;
  const int tid = threadIdx.x;
  const int lane = tid & 63;
  const int w = tid >> 6;
  const int l15 = lane & 15;
  const int g = lane >> 4;
  const size_t qkbase = (size_t)b * T_ * H_;
  const int qr0 = qb * 64 + w * 16;

  const __bf16* qp = q + qkbase + (size_t)(qr0 + l15) * H_ + g * 8;
  bf16x8 aq0 = *(const bf16x8*)qp;
  bf16x8 aq1 = *(const bf16x8*)(qp + 32);

  f32x4 accO[4];
#pragma unroll
  for (int i = 0; i < 4; ++i) accO[i] = (f32x4)0.0f;
  float mrow[4] = {-1e30f, -1e30f, -1e30f, -1e30f};
  float lsum[4] = {0.f, 0.f, 0.f, 0.f};
  char* pb = plds + w * 2048;
  const __bf16* vb = vt + (size_t)b * 64 * T_;

  const int len = (qb + 4) >> 2;  // ceil((qb+1)/4)
  const int kb0 = p * len;
  int kbend = kb0 + len;
  if (kbend > qb + 1) kbend = qb + 1;

  for (int kb = kb0; kb < kbend; ++kb) {
    const int kvb = kb * 64;
    // S = Q K^T (scale pre-folded into q)
    f32x4 s[4];
#pragma unroll
    for (int ct = 0; ct < 4; ++ct) {
      const __bf16* kp = k + qkbase + (size_t)(kvb + ct * 16 + l15) * H_ + g * 8;
      bf16x8 b0 = *(const bf16x8*)kp;
      bf16x8 b1 = *(const bf16x8*)(kp + 32);
      f32x4 z = (f32x4)0.0f;
      z = __builtin_amdgcn_mfma_f32_16x16x32_bf16(aq0, b0, z, 0, 0, 0);
      z = __builtin_amdgcn_mfma_f32_16x16x32_bf16(aq1, b1, z, 0, 0, 0);
      s[ct] = z;
    }
    if (kb == qb) {  // causal mask on diagonal block
#pragma unroll
      for (int ct = 0; ct < 4; ++ct)
#pragma unroll
        for (int r = 0; r < 4; ++r)
          if (kvb + ct * 16 + l15 > qr0 + g * 4 + r) s[ct][r] = -1e30f;
    }
    // wave-parallel online softmax (row r lives in a 16-lane group, reg r)
    float al[4];
#pragma unroll
    for (int r = 0; r < 4; ++r) {
      float v = fmaxf(fmaxf(s[0][r], s[1][r]), fmaxf(s[2][r], s[3][r]));
      v = fmaxf(v, __shfl_xor(v, 1, 64));
      v = fmaxf(v, __shfl_xor(v, 2, 64));
      v = fmaxf(v, __shfl_xor(v, 4, 64));
      v = fmaxf(v, __shfl_xor(v, 8, 64));
      float m2 = fmaxf(mrow[r], v);
      al[r] = __expf(mrow[r] - m2);
      mrow[r] = m2;
    }
#pragma unroll
    for (int ct = 0; ct < 4; ++ct)
#pragma unroll
      for (int r = 0; r < 4; ++r) s[ct][r] = __expf(s[ct][r] - mrow[r]);
#pragma unroll
    for (int r = 0; r < 4; ++r) {
      lsum[r] = lsum[r] * al[r] + (s[0][r] + s[1][r]) + (s[2][r] + s[3][r]);
#pragma unroll
      for (int hct = 0; hct < 4; ++hct) accO[hct][r] *= al[r];
    }
    // P → LDS [q][kv] (swizzled), then read back as A-fragments
#pragma unroll
    for (int ct = 0; ct < 4; ++ct)
#pragma unroll
      for (int r = 0; r < 4; ++r) {
        int qrow = g * 4 + r;
        int off = ((qrow * 64 + ct * 16 + l15) * 2) ^ ((qrow & 7) << 4);
        *(__bf16*)(pb + off) = (__bf16)s[ct][r];
      }
#pragma unroll
    for (int ks = 0; ks < 2; ++ks) {
      int off = ((l15 * 64 + ks * 32 + g * 8) * 2) ^ ((l15 & 7) << 4);
      bf16x8 pa = *(const bf16x8*)(pb + off);
#pragma unroll
      for (int hct = 0; hct < 4; ++hct) {
        const __bf16* vp = vb + (size_t)(hct * 16 + l15) * T_ + kvb + ks * 32 + g * 8;
        bf16x8 bv = *(const bf16x8*)vp;
        accO[hct] = __builtin_amdgcn_mfma_f32_16x16x32_bf16(pa, bv, accO[hct], 0, 0, 0);
      }
    }
  }
  // reduce lsum across 16-lane group; write partials (unnormalized)
#pragma unroll
  for (int r = 0; r < 4; ++r) {
    float v = lsum[r];
    v += __shfl_xor(v, 1, 64);
    v += __shfl_xor(v, 2, 64);
    v += __shfl_xor(v, 4, 64);
    v += __shfl_xor(v, 8, 64);
    lsum[r] = v;
  }
  float* op = Opart + ((size_t)p * (B_ * T_) + (size_t)b * T_ + qr0) * H_;
#pragma unroll
  for (int hct = 0; hct < 4; ++hct)
#pragma unroll
    for (int r = 0; r < 4; ++r)
      op[(size_t)(g * 4 + r) * H_ + hct * 16 + l15] = accO[hct][r];
  if (l15 == 0) {
#pragma unroll
    for (int r = 0; r < 4; ++r)
      ml[(size_t)p * (B_ * T_) + (size_t)b * T_ + qr0 + g * 4 + r] =
          make_float2(mrow[r], lsum[r]);
  }
}

// ---------------- Kernel 3: combine split-KV partials ----------------
__global__ __launch_bounds__(256) void comb_k(const float* __restrict__ Opart,
                                              const float2* __restrict__ ml,
                                              float* __restrict__ out) {
  int gid = blockIdx.x * 256 + threadIdx.x;  // 262144 = 16384 rows x 16
  int row = gid >> 4;
  int h4 = (gid & 15) * 4;
  float m[4], l[4];
#pragma unroll
  for (int p = 0; p < 4; ++p) {
    float2 t = ml[(size_t)p * (B_ * T_) + row];
    m[p] = t.x; l[p] = t.y;
  }
  float M = fmaxf(fmaxf(m[0], m[1]), fmaxf(m[2], m[3]));
  float wp[4], wsum = 0.f;
#pragma unroll
  for (int p = 0; p < 4; ++p) {
    wp[p] = __expf(m[p] - M);
    wsum += wp[p] * l[p];
  }
  float4 o = make_float4(0.f, 0.f, 0.f, 0.f);
#pragma unroll
  for (int p = 0; p < 4; ++p) {
    float4 a = *(const float4*)(Opart + ((size_t)p * (B_ * T_) + row) * H_ + h4);
    o.x += wp[p] * a.x; o.y += wp[p] * a.y; o.z += wp[p] * a.z; o.w += wp[p] * a.w;
  }
  float inv = 1.0f / wsum;
  float4 res = make_float4(o.x * inv, o.y * inv, o.z * inv, o.w * inv);
  *(float4*)(out + (size_t)row * H_ + h4) = res;
}

// ---------------- launcher ----------------
extern "C" void kernel_launch(void* const* d_in, const int* in_sizes, int n_in,
                              void* d_out, int out_size, void* d_ws, size_t ws_size,
                              hipStream_t stream) {
  const float* x  = (const float*)d_in[0];
  const float* Wq = (const float*)d_in[1];
  const float* Wk = (const float*)d_in[2];
  const float* Wv = (const float*)d_in[3];
  float* out = (float*)d_out;
  char* ws = (char*)d_ws;
  __bf16* Wt   = (__bf16*)ws;                  // 384 KiB
  __bf16* qb   = (__bf16*)(ws + 0x60000);      // 2 MiB
  __bf16* kb   = (__bf16*)(ws + 0x260000);     // 2 MiB
  __bf16* vtb  = (__bf16*)(ws + 0x460000);     // 2 MiB (vt[b][h][t])
  float*  Op   = (float*)(ws + 0x660000);      // 16 MiB (4 x 16384 x 64 f32)
  float2* mlb  = (float2*)(ws + 0x1660000);    // 512 KiB

  hipLaunchKernelGGL(prep_w_k, dim3(192), dim3(256), 0, stream, Wq, Wk, Wv, Wt);
  hipLaunchKernelGGL(qkv_k, dim3(512), dim3(512), 0, stream, x, Wt, qb, kb, vtb);
  hipLaunchKernelGGL(attn_k, dim3(1024), dim3(256), 0, stream, qb, kb, vtb, Op, mlb);
  hipLaunchKernelGGL(comb_k, dim3(1024), dim3(256), 0, stream, Op, mlb, out);
}

// Round 3
// 222.152 us; speedup vs baseline: 1.1803x; 1.0018x over previous
//
#include <hip/hip_runtime.h>
#include <hip/hip_bf16.h>

#define B_ 8
#define T_ 2048
#define C_ 1024
#define H_ 64

typedef __bf16 bf16x8 __attribute__((ext_vector_type(8)));
typedef float f32x4 __attribute__((ext_vector_type(4)));

// ---------------- Kernel 0: weight transpose + bf16 cast ----------------
__global__ __launch_bounds__(256) void prep_w_k(const float* __restrict__ Wq,
                                                const float* __restrict__ Wk,
                                                const float* __restrict__ Wv,
                                                __bf16* __restrict__ Wt) {
  int idx = blockIdx.x * 256 + threadIdx.x;  // 49152 total (3*64*256)
  int m = idx >> 14;
  int rem = idx & 16383;
  int h = rem >> 8;
  int c4 = (rem & 255) << 2;
  const float* W = (m == 0) ? Wq : ((m == 1) ? Wk : Wv);
  float sc = (m == 0) ? 0.03125f : 1.0f;
  __bf16* dst = Wt + ((size_t)(m * H_ + h)) * C_ + c4;
#pragma unroll
  for (int i = 0; i < 4; ++i) dst[i] = (__bf16)(W[(size_t)(c4 + i) * H_ + h] * sc);
}

// ---------------- Kernel 1: fused QKV projection (MFMA, prefetched) ----------------
// 512 blocks x 512 threads; 8 waves: (w&1)=row-half (16 rows), (w>>1)=col-quarter (3 tiles)
__global__ __launch_bounds__(512, 4) void qkv_k(const float* __restrict__ x,
                                                const __bf16* __restrict__ Wt,
                                                __bf16* __restrict__ q,
                                                __bf16* __restrict__ k,
                                                __bf16* __restrict__ vt) {
  __shared__ __align__(16) char vtile[64 * 32 * 2];  // [h][t_local 32] swizzled
  const int tid = threadIdx.x;
  const int lane = tid & 63;
  const int w = tid >> 6;        // 0..7
  const int l15 = lane & 15;
  const int g = lane >> 4;
  const int quarter = w >> 1;    // 0..3
  const int r0 = blockIdx.x * 32 + (w & 1) * 16;
  const int tcb = quarter * 3;   // base tile index (of 12)

  f32x4 acc0 = (f32x4)0.0f, acc1 = (f32x4)0.0f, acc2 = (f32x4)0.0f;

  const float* xp = x + (size_t)(r0 + l15) * C_ + g * 8;
  const int tc0 = tcb, tc1 = tcb + 1, tc2 = tcb + 2;
  const __bf16* bp0 = Wt + (size_t)((tc0 >> 2) * 64 + ((tc0 & 3) << 4) + l15) * C_ + g * 8;
  const __bf16* bp1 = Wt + (size_t)((tc1 >> 2) * 64 + ((tc1 & 3) << 4) + l15) * C_ + g * 8;
  const __bf16* bp2 = Wt + (size_t)((tc2 >> 2) * 64 + ((tc2 & 3) << 4) + l15) * C_ + g * 8;

  // prologue: A for kb=0,1 ; B for kb=0
  float4 cA0 = *(const float4*)(xp + 0),  cA1 = *(const float4*)(xp + 4);
  float4 dA0 = *(const float4*)(xp + 32), dA1 = *(const float4*)(xp + 36);
  bf16x8 b0 = *(const bf16x8*)bp0, b1 = *(const bf16x8*)bp1, b2 = *(const bf16x8*)bp2;

  for (int kb = 0; kb < 32; kb += 2) {
    // prefetch A for kb+2, B for kb+1
    const int a2 = (kb + 2 < 32) ? (kb + 2) : 30;
    float4 p0 = *(const float4*)(xp + a2 * 32), p1 = *(const float4*)(xp + a2 * 32 + 4);
    bf16x8 n0 = *(const bf16x8*)(bp0 + (kb + 1) * 32);
    bf16x8 n1 = *(const bf16x8*)(bp1 + (kb + 1) * 32);
    bf16x8 n2 = *(const bf16x8*)(bp2 + (kb + 1) * 32);
    // compute even kb
    bf16x8 af;
    af[0] = (__bf16)cA0.x; af[1] = (__bf16)cA0.y; af[2] = (__bf16)cA0.z; af[3] = (__bf16)cA0.w;
    af[4] = (__bf16)cA1.x; af[5] = (__bf16)cA1.y; af[6] = (__bf16)cA1.z; af[7] = (__bf16)cA1.w;
    acc0 = __builtin_amdgcn_mfma_f32_16x16x32_bf16(af, b0, acc0, 0, 0, 0);
    acc1 = __builtin_amdgcn_mfma_f32_16x16x32_bf16(af, b1, acc1, 0, 0, 0);
    acc2 = __builtin_amdgcn_mfma_f32_16x16x32_bf16(af, b2, acc2, 0, 0, 0);
    // prefetch A for kb+3, B for kb+2
    const int a3 = (kb + 3 < 32) ? (kb + 3) : 31;
    const int bk2 = (kb + 2 < 32) ? (kb + 2) : 31;
    float4 p2 = *(const float4*)(xp + a3 * 32), p3 = *(const float4*)(xp + a3 * 32 + 4);
    bf16x8 m0 = *(const bf16x8*)(bp0 + bk2 * 32);
    bf16x8 m1 = *(const bf16x8*)(bp1 + bk2 * 32);
    bf16x8 m2 = *(const bf16x8*)(bp2 + bk2 * 32);
    // compute odd kb
    af[0] = (__bf16)dA0.x; af[1] = (__bf16)dA0.y; af[2] = (__bf16)dA0.z; af[3] = (__bf16)dA0.w;
    af[4] = (__bf16)dA1.x; af[5] = (__bf16)dA1.y; af[6] = (__bf16)dA1.z; af[7] = (__bf16)dA1.w;
    acc0 = __builtin_amdgcn_mfma_f32_16x16x32_bf16(af, n0, acc0, 0, 0, 0);
    acc1 = __builtin_amdgcn_mfma_f32_16x16x32_bf16(af, n1, acc1, 0, 0, 0);
    acc2 = __builtin_amdgcn_mfma_f32_16x16x32_bf16(af, n2, acc2, 0, 0, 0);
    cA0 = p0; cA1 = p1; dA0 = p2; dA1 = p3;
    b0 = m0; b1 = m1; b2 = m2;
  }

  const int drow = r0 + g * 4;
  f32x4 accv[3] = {acc0, acc1, acc2};
#pragma unroll
  for (int ct = 0; ct < 3; ++ct) {
    int tc = tcb + ct;
    int m = tc >> 2;
    int hcol = ((tc & 3) << 4) + l15;
    if (m == 0) {
#pragma unroll
      for (int r = 0; r < 4; ++r)
        q[(size_t)(drow + r) * H_ + hcol] = (__bf16)accv[ct][r];
    } else if (m == 1) {
#pragma unroll
      for (int r = 0; r < 4; ++r)
        k[(size_t)(drow + r) * H_ + hcol] = (__bf16)accv[ct][r];
    } else {
      int tl = (w & 1) * 16 + g * 4;
      union { ushort4 u; __bf16 h[4]; } pk;
#pragma unroll
      for (int r = 0; r < 4; ++r) pk.h[r] = (__bf16)accv[ct][r];
      int off = ((hcol * 32 + tl) * 2) ^ ((hcol & 7) << 4);
      *(ushort4*)(vtile + off) = pk.u;
    }
  }
  __syncthreads();
  const int h = tid >> 3;
  const int t4 = (tid & 7) * 4;
  int off = ((h * 32 + t4) * 2) ^ ((h & 7) << 4);
  unsigned long long v = *(const unsigned long long*)(vtile + off);
  int bb = blockIdx.x >> 6;
  int tglob = (blockIdx.x & 63) * 32 + t4;
  *(unsigned long long*)(vt + ((size_t)bb * 64 + h) * T_ + tglob) = v;
}

// ---------------- Kernel 2: causal flash attention, split-KV x4, prefetched ----------------
__global__ __launch_bounds__(256, 3) void attn_k(const __bf16* __restrict__ q,
                                                 const __bf16* __restrict__ k,
                                                 const __bf16* __restrict__ vt,
                                                 float* __restrict__ Opart,
                                                 float2* __restrict__ ml) {
  __shared__ __align__(16) char plds[4 * 16 * 64 * 2];  // per-wave P tile [q][kv] swizzled
  const int bid = blockIdx.x;
  const int p = bid & 3;
  const int qb = (bid >> 2) & 31;
  const int b = bid >> 7;
  const int tid = threadIdx.x;
  const int lane = tid & 63;
  const int w = tid >> 6;
  const int l15 = lane & 15;
  const int g = lane >> 4;
  const size_t qkbase = (size_t)b * T_ * H_;
  const int qr0 = qb * 64 + w * 16;

  const __bf16* qp = q + qkbase + (size_t)(qr0 + l15) * H_ + g * 8;
  bf16x8 aq0 = *(const bf16x8*)qp;
  bf16x8 aq1 = *(const bf16x8*)(qp + 32);

  f32x4 accO[4];
#pragma unroll
  for (int i = 0; i < 4; ++i) accO[i] = (f32x4)0.0f;
  float mrow[4] = {-1e30f, -1e30f, -1e30f, -1e30f};
  float lsum[4] = {0.f, 0.f, 0.f, 0.f};
  char* pb = plds + w * 2048;
  const __bf16* vb = vt + (size_t)b * 64 * T_;
  const __bf16* kbase = k + qkbase + (size_t)l15 * H_ + g * 8;

  const int len = (qb + 4) >> 2;  // ceil((qb+1)/4)
  const int kb0 = p * len;
  int kbend = kb0 + len;
  if (kbend > qb + 1) kbend = qb + 1;

  if (kb0 < kbend) {
    // prologue: K frags for kb0
    bf16x8 kc[4][2];
#pragma unroll
    for (int ct = 0; ct < 4; ++ct) {
      const __bf16* kp = kbase + (size_t)(kb0 * 64 + ct * 16) * H_;
      kc[ct][0] = *(const bf16x8*)kp;
      kc[ct][1] = *(const bf16x8*)(kp + 32);
    }

    for (int kb = kb0; kb < kbend; ++kb) {
      const int kvb = kb * 64;
      // issue V loads for this kb (independent of softmax chain)
      bf16x8 vv[2][4];
#pragma unroll
      for (int ks = 0; ks < 2; ++ks)
#pragma unroll
        for (int hct = 0; hct < 4; ++hct)
          vv[ks][hct] = *(const bf16x8*)(vb + (size_t)(hct * 16 + l15) * T_ +
                                         kvb + ks * 32 + g * 8);
      // prefetch K frags for next kb
      const int nkb = (kb + 1 < kbend) ? (kb + 1) : kb;
      bf16x8 kn[4][2];
#pragma unroll
      for (int ct = 0; ct < 4; ++ct) {
        const __bf16* kp = kbase + (size_t)(nkb * 64 + ct * 16) * H_;
        kn[ct][0] = *(const bf16x8*)kp;
        kn[ct][1] = *(const bf16x8*)(kp + 32);
      }
      // S = Q K^T (scale pre-folded into q)
      f32x4 s[4];
#pragma unroll
      for (int ct = 0; ct < 4; ++ct) {
        f32x4 z = (f32x4)0.0f;
        z = __builtin_amdgcn_mfma_f32_16x16x32_bf16(aq0, kc[ct][0], z, 0, 0, 0);
        z = __builtin_amdgcn_mfma_f32_16x16x32_bf16(aq1, kc[ct][1], z, 0, 0, 0);
        s[ct] = z;
      }
      if (kb == qb) {  // causal mask on diagonal block
#pragma unroll
        for (int ct = 0; ct < 4; ++ct)
#pragma unroll
          for (int r = 0; r < 4; ++r)
            if (kvb + ct * 16 + l15 > qr0 + g * 4 + r) s[ct][r] = -1e30f;
      }
      // wave-parallel online softmax
      float al[4];
#pragma unroll
      for (int r = 0; r < 4; ++r) {
        float v = fmaxf(fmaxf(s[0][r], s[1][r]), fmaxf(s[2][r], s[3][r]));
        v = fmaxf(v, __shfl_xor(v, 1, 64));
        v = fmaxf(v, __shfl_xor(v, 2, 64));
        v = fmaxf(v, __shfl_xor(v, 4, 64));
        v = fmaxf(v, __shfl_xor(v, 8, 64));
        float m2 = fmaxf(mrow[r], v);
        al[r] = __expf(mrow[r] - m2);
        mrow[r] = m2;
      }
#pragma unroll
      for (int ct = 0; ct < 4; ++ct)
#pragma unroll
        for (int r = 0; r < 4; ++r) s[ct][r] = __expf(s[ct][r] - mrow[r]);
#pragma unroll
      for (int r = 0; r < 4; ++r) {
        lsum[r] = lsum[r] * al[r] + (s[0][r] + s[1][r]) + (s[2][r] + s[3][r]);
#pragma unroll
        for (int hct = 0; hct < 4; ++hct) accO[hct][r] *= al[r];
      }
      // P → LDS [q][kv] (swizzled), read back as A-fragments
#pragma unroll
      for (int ct = 0; ct < 4; ++ct)
#pragma unroll
        for (int r = 0; r < 4; ++r) {
          int qrow = g * 4 + r;
          int off = ((qrow * 64 + ct * 16 + l15) * 2) ^ ((qrow & 7) << 4);
          *(__bf16*)(pb + off) = (__bf16)s[ct][r];
        }
#pragma unroll
      for (int ks = 0; ks < 2; ++ks) {
        int off = ((l15 * 64 + ks * 32 + g * 8) * 2) ^ ((l15 & 7) << 4);
        bf16x8 pa = *(const bf16x8*)(pb + off);
#pragma unroll
        for (int hct = 0; hct < 4; ++hct)
          accO[hct] = __builtin_amdgcn_mfma_f32_16x16x32_bf16(pa, vv[ks][hct], accO[hct], 0, 0, 0);
      }
      // rotate prefetched K
#pragma unroll
      for (int ct = 0; ct < 4; ++ct) {
        kc[ct][0] = kn[ct][0];
        kc[ct][1] = kn[ct][1];
      }
    }
  }
  // reduce lsum across 16-lane group; write partials (unnormalized)
#pragma unroll
  for (int r = 0; r < 4; ++r) {
    float v = lsum[r];
    v += __shfl_xor(v, 1, 64);
    v += __shfl_xor(v, 2, 64);
    v += __shfl_xor(v, 4, 64);
    v += __shfl_xor(v, 8, 64);
    lsum[r] = v;
  }
  float* op = Opart + ((size_t)p * (B_ * T_) + (size_t)b * T_ + qr0) * H_;
#pragma unroll
  for (int hct = 0; hct < 4; ++hct)
#pragma unroll
    for (int r = 0; r < 4; ++r)
      op[(size_t)(g * 4 + r) * H_ + hct * 16 + l15] = accO[hct][r];
  if (l15 == 0) {
#pragma unroll
    for (int r = 0; r < 4; ++r)
      ml[(size_t)p * (B_ * T_) + (size_t)b * T_ + qr0 + g * 4 + r] =
          make_float2(mrow[r], lsum[r]);
  }
}

// ---------------- Kernel 3: combine split-KV partials ----------------
__global__ __launch_bounds__(256) void comb_k(const float* __restrict__ Opart,
                                              const float2* __restrict__ ml,
                                              float* __restrict__ out) {
  int gid = blockIdx.x * 256 + threadIdx.x;  // 262144 = 16384 rows x 16
  int row = gid >> 4;
  int h4 = (gid & 15) * 4;
  float m[4], l[4];
#pragma unroll
  for (int p = 0; p < 4; ++p) {
    float2 t = ml[(size_t)p * (B_ * T_) + row];
    m[p] = t.x; l[p] = t.y;
  }
  float M = fmaxf(fmaxf(m[0], m[1]), fmaxf(m[2], m[3]));
  float wp[4], wsum = 0.f;
#pragma unroll
  for (int p = 0; p < 4; ++p) {
    wp[p] = __expf(m[p] - M);
    wsum += wp[p] * l[p];
  }
  float4 o = make_float4(0.f, 0.f, 0.f, 0.f);
#pragma unroll
  for (int p = 0; p < 4; ++p) {
    float4 a = *(const float4*)(Opart + ((size_t)p * (B_ * T_) + row) * H_ + h4);
    o.x += wp[p] * a.x; o.y += wp[p] * a.y; o.z += wp[p] * a.z; o.w += wp[p] * a.w;
  }
  float inv = 1.0f / wsum;
  float4 res = make_float4(o.x * inv, o.y * inv, o.z * inv, o.w * inv);
  *(float4*)(out + (size_t)row * H_ + h4) = res;
}

// ---------------- launcher ----------------
extern "C" void kernel_launch(void* const* d_in, const int* in_sizes, int n_in,
                              void* d_out, int out_size, void* d_ws, size_t ws_size,
                              hipStream_t stream) {
  const float* x  = (const float*)d_in[0];
  const float* Wq = (const float*)d_in[1];
  const float* Wk = (const float*)d_in[2];
  const float* Wv = (const float*)d_in[3];
  float* out = (float*)d_out;
  char* ws = (char*)d_ws;
  __bf16* Wt   = (__bf16*)ws;                  // 384 KiB
  __bf16* qb   = (__bf16*)(ws + 0x60000);      // 2 MiB
  __bf16* kb   = (__bf16*)(ws + 0x260000);     // 2 MiB
  __bf16* vtb  = (__bf16*)(ws + 0x460000);     // 2 MiB (vt[b][h][t])
  float*  Op   = (float*)(ws + 0x660000);      // 16 MiB (4 x 16384 x 64 f32)
  float2* mlb  = (float2*)(ws + 0x1660000);    // 512 KiB

  hipLaunchKernelGGL(prep_w_k, dim3(192), dim3(256), 0, stream, Wq, Wk, Wv, Wt);
  hipLaunchKernelGGL(qkv_k, dim3(512), dim3(512), 0, stream, x, Wt, qb, kb, vtb);
  hipLaunchKernelGGL(attn_k, dim3(1024), dim3(256), 0, stream, qb, kb, vtb, Op, mlb);
  hipLaunchKernelGGL(comb_k, dim3(1024), dim3(256), 0, stream, Op, mlb, out);
}

// Round 4
// 188.510 us; speedup vs baseline: 1.3909x; 1.1785x over previous
//
#include <hip/hip_runtime.h>
#include <hip/hip_bf16.h>

#define B_ 8
#define T_ 2048
#define C_ 1024
#define H_ 64

typedef __bf16 bf16x8 __attribute__((ext_vector_type(8)));
typedef float f32x4 __attribute__((ext_vector_type(4)));

typedef __attribute__((address_space(3))) unsigned int lds_u32;
typedef const __attribute__((address_space(1))) unsigned int glb_u32;
__device__ __forceinline__ void gl_lds16(const void* gp, void* lp) {
  __builtin_amdgcn_global_load_lds((glb_u32*)gp, (lds_u32*)lp, 16, 0, 0);
}

// ---------------- Kernel 0: weight transpose + bf16 cast ----------------
// Wt[m][h][c] = W_m[c][h] (* 1/32 for m==0, folding in scale = C^-0.5)
__global__ __launch_bounds__(256) void prep_w_k(const float* __restrict__ Wq,
                                                const float* __restrict__ Wk,
                                                const float* __restrict__ Wv,
                                                __bf16* __restrict__ Wt) {
  int idx = blockIdx.x * 256 + threadIdx.x;  // 49152 total (3*64*256)
  int m = idx >> 14;
  int rem = idx & 16383;
  int h = rem >> 8;
  int c4 = (rem & 255) << 2;
  const float* W = (m == 0) ? Wq : ((m == 1) ? Wk : Wv);
  float sc = (m == 0) ? 0.03125f : 1.0f;
  __bf16* dst = Wt + ((size_t)(m * H_ + h)) * C_ + c4;
#pragma unroll
  for (int i = 0; i < 4; ++i) dst[i] = (__bf16)(W[(size_t)(c4 + i) * H_ + h] * sc);
}

// ---------------- Kernel 1: QKV projection, global_load_lds 2-phase pipeline ----------------
// grid 512 (32 rows each), 256 thr = 4 waves; wave wc covers 32 rows x 48 cols.
// LDS per buffer: A = 32 rows x 128 B (f32, XOR-swz 16B chunks) = 4 KB;
//                 B = 4 g-planes x 192 cols x 16 B = 12 KB. Two buffers = 32 KB.
__global__ __launch_bounds__(256) void qkv_k(const float* __restrict__ x,
                                             const __bf16* __restrict__ Wt,
                                             __bf16* __restrict__ q,
                                             __bf16* __restrict__ kk,
                                             __bf16* __restrict__ vt) {
  __shared__ __align__(16) char smem[32768];
  const int tid = threadIdx.x;
  const int lane = tid & 63;
  const int wc = tid >> 6;     // wave = col-quarter
  const int l15 = lane & 15;
  const int g = lane >> 4;
  const int row0 = blockIdx.x * 32;

  // ---- staging address precompute ----
  // A: 256 thr x 16 B = 4 KB/step. LDS linear [row][chunk]; source chunk XOR (row&7).
  const int srow = tid >> 3;                   // 0..31
  const int sch = (tid & 7) ^ (srow & 7);
  const char* agsrc = (const char*)(x + (size_t)(row0 + srow) * C_) + sch * 16;
  const int adst = tid * 16;
  // B: 3 issues; chunk c = i*256+tid -> plane g, col. src = Wt[col][kb*32 + g*8..]
  int bg[3], bcol[3];
  const char* bgs[3];
#pragma unroll
  for (int i = 0; i < 3; ++i) {
    int c = i * 256 + tid;
    bg[i] = c / 192;
    bcol[i] = c - bg[i] * 192;
    bgs[i] = (const char*)Wt + bcol[i] * 2048 + bg[i] * 16;
  }
  const int bdst0 = 4096 + (0 * 256 + tid) * 16;
  const int bdst1 = 4096 + (1 * 256 + tid) * 16;
  const int bdst2 = 4096 + (2 * 256 + tid) * 16;

  f32x4 acc[2][3];
#pragma unroll
  for (int rt = 0; rt < 2; ++rt)
#pragma unroll
    for (int ctl = 0; ctl < 3; ++ctl) acc[rt][ctl] = (f32x4)0.0f;

  // ---- prologue: stage kb=0 into buf0 ----
  gl_lds16(agsrc, smem + adst);
  gl_lds16(bgs[0], smem + bdst0);
  gl_lds16(bgs[1], smem + bdst1);
  gl_lds16(bgs[2], smem + bdst2);
  asm volatile("s_waitcnt vmcnt(0)" ::: "memory");
  __syncthreads();

  for (int t = 0; t < 32; ++t) {
    const int cur = (t & 1) << 14;
    if (t < 31) {
      const int nxt = ((t + 1) & 1) << 14;
      const size_t ao = (size_t)(t + 1) << 7;   // 128 B per K-step (A)
      const size_t bo = (size_t)(t + 1) << 6;   // 64 B per K-step (B)
      gl_lds16(agsrc + ao, smem + nxt + adst);
      gl_lds16(bgs[0] + bo, smem + nxt + bdst0);
      gl_lds16(bgs[1] + bo, smem + nxt + bdst1);
      gl_lds16(bgs[2] + bo, smem + nxt + bdst2);
    }
    // ---- compute current buffer ----
    bf16x8 af[2];
#pragma unroll
    for (int rt = 0; rt < 2; ++rt) {
      const int row = rt * 16 + l15;
      const char* ab = smem + cur + row * 128;
      f32x4 a0 = *(const f32x4*)(ab + ((((g << 1)) ^ (row & 7)) << 4));
      f32x4 a1 = *(const f32x4*)(ab + ((((g << 1) | 1) ^ (row & 7)) << 4));
#pragma unroll
      for (int j = 0; j < 4; ++j) {
        af[rt][j] = (__bf16)a0[j];
        af[rt][4 + j] = (__bf16)a1[j];
      }
    }
#pragma unroll
    for (int ctl = 0; ctl < 3; ++ctl) {
      const int col = wc * 48 + ctl * 16 + l15;
      bf16x8 bf = *(const bf16x8*)(smem + cur + 4096 + g * 3072 + col * 16);
      acc[0][ctl] = __builtin_amdgcn_mfma_f32_16x16x32_bf16(af[0], bf, acc[0][ctl], 0, 0, 0);
      acc[1][ctl] = __builtin_amdgcn_mfma_f32_16x16x32_bf16(af[1], bf, acc[1][ctl], 0, 0, 0);
    }
    asm volatile("s_waitcnt vmcnt(0)" ::: "memory");
    __syncthreads();
  }

  // ---- epilogue: q/k direct, v via swizzled LDS transpose -> vt[b][h][t] ----
#pragma unroll
  for (int rt = 0; rt < 2; ++rt)
#pragma unroll
    for (int ctl = 0; ctl < 3; ++ctl) {
      const int cb = wc * 48 + ctl * 16;
      const int m = cb >> 6;
      const int drow = row0 + rt * 16 + g * 4;
      if (m == 0) {
#pragma unroll
        for (int r = 0; r < 4; ++r)
          q[(size_t)(drow + r) * H_ + (cb & 63) + l15] = (__bf16)acc[rt][ctl][r];
      } else if (m == 1) {
#pragma unroll
        for (int r = 0; r < 4; ++r)
          kk[(size_t)(drow + r) * H_ + (cb & 63) + l15] = (__bf16)acc[rt][ctl][r];
      } else {
        const int vh = (cb - 128) + l15;
        const int t0 = rt * 16 + g * 4;
        union { ushort4 u; __bf16 h[4]; } pk;
#pragma unroll
        for (int r = 0; r < 4; ++r) pk.h[r] = (__bf16)acc[rt][ctl][r];
        int off = ((vh * 32 + t0) * 2) ^ ((vh & 7) << 4);
        *(ushort4*)(smem + off) = pk.u;
      }
    }
  __syncthreads();
  {
    const int h = tid >> 2;
    const int t8 = (tid & 3) * 8;
    const int sw = (h & 7) << 4;
    unsigned long long u0 = *(const unsigned long long*)(smem + (((h * 32 + t8) * 2) ^ sw));
    unsigned long long u1 = *(const unsigned long long*)(smem + (((h * 32 + t8 + 4) * 2) ^ sw));
    const int bb = blockIdx.x >> 6;
    const int tglob = (blockIdx.x & 63) * 32 + t8;
    unsigned long long* dst =
        (unsigned long long*)(vt + ((size_t)bb * 64 + h) * T_ + tglob);
    dst[0] = u0;
    dst[1] = u1;
  }
}

// ---------------- Kernel 2: causal flash attention, split-KV ----------------
// grid = b(8) x qb(32) x piece(SPLIT); 4 waves x 16 q-rows; KVBLK=64
template <int SPLIT>
__global__ __launch_bounds__(256) void attn_k(const __bf16* __restrict__ q,
                                              const __bf16* __restrict__ k,
                                              const __bf16* __restrict__ vt,
                                              float* __restrict__ Opart,
                                              float2* __restrict__ ml) {
  __shared__ __align__(16) char plds[4 * 16 * 64 * 2];  // per-wave P tile [q][kv] swizzled
  const int bid = blockIdx.x;
  const int p = bid % SPLIT;
  const int qb = (bid / SPLIT) & 31;
  const int b = bid / (SPLIT * 32);
  const int tid = threadIdx.x;
  const int lane = tid & 63;
  const int w = tid >> 6;
  const int l15 = lane & 15;
  const int g = lane >> 4;
  const size_t qkbase = (size_t)b * T_ * H_;
  const int qr0 = qb * 64 + w * 16;

  const __bf16* qp = q + qkbase + (size_t)(qr0 + l15) * H_ + g * 8;
  bf16x8 aq0 = *(const bf16x8*)qp;
  bf16x8 aq1 = *(const bf16x8*)(qp + 32);

  f32x4 accO[4];
#pragma unroll
  for (int i = 0; i < 4; ++i) accO[i] = (f32x4)0.0f;
  float mrow[4] = {-1e30f, -1e30f, -1e30f, -1e30f};
  float lsum[4] = {0.f, 0.f, 0.f, 0.f};
  char* pb = plds + w * 2048;
  const __bf16* vb = vt + (size_t)b * 64 * T_;

  const int len = (qb + SPLIT) / SPLIT;  // ceil((qb+1)/SPLIT)
  const int kb0 = p * len;
  int kbend = kb0 + len;
  if (kbend > qb + 1) kbend = qb + 1;

  for (int kb = kb0; kb < kbend; ++kb) {
    const int kvb = kb * 64;
    // issue V loads early (independent of softmax chain)
    bf16x8 vv[2][4];
#pragma unroll
    for (int ks = 0; ks < 2; ++ks)
#pragma unroll
      for (int hct = 0; hct < 4; ++hct)
        vv[ks][hct] = *(const bf16x8*)(vb + (size_t)(hct * 16 + l15) * T_ +
                                       kvb + ks * 32 + g * 8);
    // S = Q K^T (scale pre-folded into q)
    f32x4 s[4];
#pragma unroll
    for (int ct = 0; ct < 4; ++ct) {
      const __bf16* kp = k + qkbase + (size_t)(kvb + ct * 16 + l15) * H_ + g * 8;
      bf16x8 b0 = *(const bf16x8*)kp;
      bf16x8 b1 = *(const bf16x8*)(kp + 32);
      f32x4 z = (f32x4)0.0f;
      z = __builtin_amdgcn_mfma_f32_16x16x32_bf16(aq0, b0, z, 0, 0, 0);
      z = __builtin_amdgcn_mfma_f32_16x16x32_bf16(aq1, b1, z, 0, 0, 0);
      s[ct] = z;
    }
    if (kb == qb) {  // causal mask on diagonal block
#pragma unroll
      for (int ct = 0; ct < 4; ++ct)
#pragma unroll
        for (int r = 0; r < 4; ++r)
          if (kvb + ct * 16 + l15 > qr0 + g * 4 + r) s[ct][r] = -1e30f;
    }
    // wave-parallel online softmax
    float al[4];
#pragma unroll
    for (int r = 0; r < 4; ++r) {
      float v = fmaxf(fmaxf(s[0][r], s[1][r]), fmaxf(s[2][r], s[3][r]));
      v = fmaxf(v, __shfl_xor(v, 1, 64));
      v = fmaxf(v, __shfl_xor(v, 2, 64));
      v = fmaxf(v, __shfl_xor(v, 4, 64));
      v = fmaxf(v, __shfl_xor(v, 8, 64));
      float m2 = fmaxf(mrow[r], v);
      al[r] = __expf(mrow[r] - m2);
      mrow[r] = m2;
    }
#pragma unroll
    for (int ct = 0; ct < 4; ++ct)
#pragma unroll
      for (int r = 0; r < 4; ++r) s[ct][r] = __expf(s[ct][r] - mrow[r]);
#pragma unroll
    for (int r = 0; r < 4; ++r) {
      lsum[r] = lsum[r] * al[r] + (s[0][r] + s[1][r]) + (s[2][r] + s[3][r]);
#pragma unroll
      for (int hct = 0; hct < 4; ++hct) accO[hct][r] *= al[r];
    }
    // P -> LDS [q][kv] (swizzled), read back as A-fragments
#pragma unroll
    for (int ct = 0; ct < 4; ++ct)
#pragma unroll
      for (int r = 0; r < 4; ++r) {
        int qrow = g * 4 + r;
        int off = ((qrow * 64 + ct * 16 + l15) * 2) ^ ((qrow & 7) << 4);
        *(__bf16*)(pb + off) = (__bf16)s[ct][r];
      }
#pragma unroll
    for (int ks = 0; ks < 2; ++ks) {
      int off = ((l15 * 64 + ks * 32 + g * 8) * 2) ^ ((l15 & 7) << 4);
      bf16x8 pa = *(const bf16x8*)(pb + off);
#pragma unroll
      for (int hct = 0; hct < 4; ++hct)
        accO[hct] = __builtin_amdgcn_mfma_f32_16x16x32_bf16(pa, vv[ks][hct], accO[hct], 0, 0, 0);
    }
  }
  // reduce lsum across 16-lane group; write partials (unnormalized)
#pragma unroll
  for (int r = 0; r < 4; ++r) {
    float v = lsum[r];
    v += __shfl_xor(v, 1, 64);
    v += __shfl_xor(v, 2, 64);
    v += __shfl_xor(v, 4, 64);
    v += __shfl_xor(v, 8, 64);
    lsum[r] = v;
  }
  float* op = Opart + ((size_t)p * (B_ * T_) + (size_t)b * T_ + qr0) * H_;
#pragma unroll
  for (int hct = 0; hct < 4; ++hct)
#pragma unroll
    for (int r = 0; r < 4; ++r)
      op[(size_t)(g * 4 + r) * H_ + hct * 16 + l15] = accO[hct][r];
  if (l15 == 0) {
#pragma unroll
    for (int r = 0; r < 4; ++r)
      ml[(size_t)p * (B_ * T_) + (size_t)b * T_ + qr0 + g * 4 + r] =
          make_float2(mrow[r], lsum[r]);
  }
}

// ---------------- Kernel 3: combine split-KV partials ----------------
template <int SPLIT>
__global__ __launch_bounds__(256) void comb_k(const float* __restrict__ Opart,
                                              const float2* __restrict__ ml,
                                              float* __restrict__ out) {
  int gid = blockIdx.x * 256 + threadIdx.x;  // 262144 = 16384 rows x 16
  int row = gid >> 4;
  int h4 = (gid & 15) * 4;
  float m[SPLIT], l[SPLIT];
#pragma unroll
  for (int p = 0; p < SPLIT; ++p) {
    float2 t = ml[(size_t)p * (B_ * T_) + row];
    m[p] = t.x;
    l[p] = t.y;
  }
  float M = -1e30f;
#pragma unroll
  for (int p = 0; p < SPLIT; ++p) M = fmaxf(M, m[p]);
  float wp[SPLIT], wsum = 0.f;
#pragma unroll
  for (int p = 0; p < SPLIT; ++p) {
    wp[p] = __expf(m[p] - M);
    wsum += wp[p] * l[p];
  }
  float4 o = make_float4(0.f, 0.f, 0.f, 0.f);
#pragma unroll
  for (int p = 0; p < SPLIT; ++p) {
    float4 a = *(const float4*)(Opart + ((size_t)p * (B_ * T_) + row) * H_ + h4);
    o.x += wp[p] * a.x;
    o.y += wp[p] * a.y;
    o.z += wp[p] * a.z;
    o.w += wp[p] * a.w;
  }
  float inv = 1.0f / wsum;
  *(float4*)(out + (size_t)row * H_ + h4) =
      make_float4(o.x * inv, o.y * inv, o.z * inv, o.w * inv);
}

// ---------------- launcher ----------------
extern "C" void kernel_launch(void* const* d_in, const int* in_sizes, int n_in,
                              void* d_out, int out_size, void* d_ws, size_t ws_size,
                              hipStream_t stream) {
  const float* x  = (const float*)d_in[0];
  const float* Wq = (const float*)d_in[1];
  const float* Wk = (const float*)d_in[2];
  const float* Wv = (const float*)d_in[3];
  float* out = (float*)d_out;
  char* ws = (char*)d_ws;
  __bf16* Wt   = (__bf16*)ws;                  // 384 KiB
  __bf16* qb   = (__bf16*)(ws + 0x60000);      // 2 MiB
  __bf16* kb   = (__bf16*)(ws + 0x260000);     // 2 MiB
  __bf16* vtb  = (__bf16*)(ws + 0x460000);     // 2 MiB (vt[b][h][t])
  const size_t opOff = 0x660000;
  float* Op = (float*)(ws + opOff);

  hipLaunchKernelGGL(prep_w_k, dim3(192), dim3(256), 0, stream, Wq, Wk, Wv, Wt);
  hipLaunchKernelGGL(qkv_k, dim3(512), dim3(256), 0, stream, x, Wt, qb, kb, vtb);

  const size_t opBytes8 = (size_t)8 * B_ * T_ * H_ * 4;
  const size_t need8 = opOff + opBytes8 + (size_t)8 * B_ * T_ * sizeof(float2);
  if (ws_size >= need8) {
    float2* mlb = (float2*)(ws + opOff + opBytes8);
    hipLaunchKernelGGL(attn_k<8>, dim3(8 * 32 * 8), dim3(256), 0, stream, qb, kb, vtb, Op, mlb);
    hipLaunchKernelGGL(comb_k<8>, dim3(1024), dim3(256), 0, stream, Op, mlb, out);
  } else {
    const size_t opBytes4 = (size_t)4 * B_ * T_ * H_ * 4;
    float2* mlb = (float2*)(ws + opOff + opBytes4);
    hipLaunchKernelGGL(attn_k<4>, dim3(8 * 32 * 4), dim3(256), 0, stream, qb, kb, vtb, Op, mlb);
    hipLaunchKernelGGL(comb_k<4>, dim3(1024), dim3(256), 0, stream, Op, mlb, out);
  }
}

// Round 5
// 161.720 us; speedup vs baseline: 1.6214x; 1.1657x over previous
//
#include <hip/hip_runtime.h>
#include <hip/hip_bf16.h>

#define B_ 8
#define T_ 2048
#define C_ 1024
#define H_ 64

typedef __bf16 bf16x8 __attribute__((ext_vector_type(8)));
typedef float f32x4 __attribute__((ext_vector_type(4)));

typedef __attribute__((address_space(3))) unsigned int lds_u32;
typedef const __attribute__((address_space(1))) unsigned int glb_u32;
__device__ __forceinline__ void gl_lds16(const void* gp, void* lp) {
  __builtin_amdgcn_global_load_lds((glb_u32*)gp, (lds_u32*)lp, 16, 0, 0);
}

// ---------------- Kernel 0: weight transpose + bf16 cast ----------------
// Wt[m][h][c] = W_m[c][h] (* 1/32 for m==0, folding in scale = C^-0.5)
__global__ __launch_bounds__(256) void prep_w_k(const float* __restrict__ Wq,
                                                const float* __restrict__ Wk,
                                                const float* __restrict__ Wv,
                                                __bf16* __restrict__ Wt) {
  int idx = blockIdx.x * 256 + threadIdx.x;  // 49152 total (3*64*256)
  int m = idx >> 14;
  int rem = idx & 16383;
  int h = rem >> 8;
  int c4 = (rem & 255) << 2;
  const float* W = (m == 0) ? Wq : ((m == 1) ? Wk : Wv);
  float sc = (m == 0) ? 0.03125f : 1.0f;
  __bf16* dst = Wt + ((size_t)(m * H_ + h)) * C_ + c4;
#pragma unroll
  for (int i = 0; i < 4; ++i) dst[i] = (__bf16)(W[(size_t)(c4 + i) * H_ + h] * sc);
}

// ---------------- Kernel 1: QKV projection, 3-deep gl_lds pipeline ----------------
// grid 512 (32 rows each), 256 thr = 4 waves; wave wc covers 32 rows x 48 cols.
// Ring of 3 buffers x 16 KB: A = 32x128B (f32, XOR-swz 16B chunks), B = 4 planes x 192 x 16B.
__global__ __launch_bounds__(256) void qkv_k(const float* __restrict__ x,
                                             const __bf16* __restrict__ Wt,
                                             __bf16* __restrict__ q,
                                             __bf16* __restrict__ kk,
                                             __bf16* __restrict__ vt) {
  __shared__ __align__(16) char smem[49152];
  const int tid = threadIdx.x;
  const int lane = tid & 63;
  const int wc = tid >> 6;     // wave = col-quarter
  const int l15 = lane & 15;
  const int g = lane >> 4;
  const int row0 = blockIdx.x * 32;

  // staging addresses
  const int srow = tid >> 3;                   // 0..31
  const int sch = (tid & 7) ^ (srow & 7);      // source pre-swizzle
  const char* agsrc = (const char*)(x + (size_t)(row0 + srow) * C_) + sch * 16;
  const int adst = tid * 16;
  const char* bgs[3];
#pragma unroll
  for (int i = 0; i < 3; ++i) {
    int c = i * 256 + tid;
    int bg = c / 192;
    int bcol = c - bg * 192;
    bgs[i] = (const char*)Wt + bcol * 2048 + bg * 16;
  }
  const int bdst = 4096 + tid * 16;

  f32x4 acc[2][3];
#pragma unroll
  for (int rt = 0; rt < 2; ++rt)
#pragma unroll
    for (int ctl = 0; ctl < 3; ++ctl) acc[rt][ctl] = (f32x4)0.0f;

  auto stage = [&](int t, int bufo) {
    const size_t ao = (size_t)t << 7;   // 128 B per K-step (A)
    const size_t bo = (size_t)t << 6;   // 64 B per K-step (B)
    gl_lds16(agsrc + ao, smem + bufo + adst);
    gl_lds16(bgs[0] + bo, smem + bufo + bdst);
    gl_lds16(bgs[1] + bo, smem + bufo + 4096 + bdst);
    gl_lds16(bgs[2] + bo, smem + bufo + 8192 + bdst);
  };

  // prologue: stage t=0, t=1
  stage(0, 0);
  stage(1, 16384);
  int cur = 0, nxt = 16384, thr = 32768;

  for (int t = 0; t < 32; ++t) {
    if (t < 31) {
      asm volatile("s_waitcnt vmcnt(4)" ::: "memory");
    } else {
      asm volatile("s_waitcnt vmcnt(0)" ::: "memory");
    }
    __builtin_amdgcn_s_barrier();
    asm volatile("" ::: "memory");
    if (t + 2 < 32) stage(t + 2, thr);
    // compute from cur
    bf16x8 af[2];
#pragma unroll
    for (int rt = 0; rt < 2; ++rt) {
      const int row = rt * 16 + l15;
      const char* ab = smem + cur + row * 128;
      f32x4 a0 = *(const f32x4*)(ab + ((((g << 1)) ^ (row & 7)) << 4));
      f32x4 a1 = *(const f32x4*)(ab + ((((g << 1) | 1) ^ (row & 7)) << 4));
#pragma unroll
      for (int j = 0; j < 4; ++j) {
        af[rt][j] = (__bf16)a0[j];
        af[rt][4 + j] = (__bf16)a1[j];
      }
    }
#pragma unroll
    for (int ctl = 0; ctl < 3; ++ctl) {
      const int col = wc * 48 + ctl * 16 + l15;
      bf16x8 bf = *(const bf16x8*)(smem + cur + 4096 + g * 3072 + col * 16);
      acc[0][ctl] = __builtin_amdgcn_mfma_f32_16x16x32_bf16(af[0], bf, acc[0][ctl], 0, 0, 0);
      acc[1][ctl] = __builtin_amdgcn_mfma_f32_16x16x32_bf16(af[1], bf, acc[1][ctl], 0, 0, 0);
    }
    int tmp = cur; cur = nxt; nxt = thr; thr = tmp;
  }

  // epilogue: q/k direct, v via swizzled LDS transpose -> vt[b][h][t]
  // (vtile lives in smem[0,4096) = ring buffer 0; final compute used buffer 1 — no overlap)
#pragma unroll
  for (int rt = 0; rt < 2; ++rt)
#pragma unroll
    for (int ctl = 0; ctl < 3; ++ctl) {
      const int cb = wc * 48 + ctl * 16;
      const int m = cb >> 6;
      const int drow = row0 + rt * 16 + g * 4;
      if (m == 0) {
#pragma unroll
        for (int r = 0; r < 4; ++r)
          q[(size_t)(drow + r) * H_ + (cb & 63) + l15] = (__bf16)acc[rt][ctl][r];
      } else if (m == 1) {
#pragma unroll
        for (int r = 0; r < 4; ++r)
          kk[(size_t)(drow + r) * H_ + (cb & 63) + l15] = (__bf16)acc[rt][ctl][r];
      } else {
        const int vh = (cb - 128) + l15;
        const int t0 = rt * 16 + g * 4;
        union { ushort4 u; __bf16 h[4]; } pk;
#pragma unroll
        for (int r = 0; r < 4; ++r) pk.h[r] = (__bf16)acc[rt][ctl][r];
        int off = ((vh * 32 + t0) * 2) ^ ((vh & 7) << 4);
        *(ushort4*)(smem + off) = pk.u;
      }
    }
  __syncthreads();
  {
    const int h = tid >> 2;
    const int t8 = (tid & 3) * 8;
    const int sw = (h & 7) << 4;
    unsigned long long u0 = *(const unsigned long long*)(smem + (((h * 32 + t8) * 2) ^ sw));
    unsigned long long u1 = *(const unsigned long long*)(smem + (((h * 32 + t8 + 4) * 2) ^ sw));
    const int bb = blockIdx.x >> 6;
    const int tglob = (blockIdx.x & 63) * 32 + t8;
    unsigned long long* dst =
        (unsigned long long*)(vt + ((size_t)bb * 64 + h) * T_ + tglob);
    dst[0] = u0;
    dst[1] = u1;
  }
}

// ---------------- Kernel 2: causal flash attention, split-KV, LDS-staged K/V ----------------
// grid = b(8) x qb(32) x piece(SPLIT); 4 waves x 16 q-rows; KVBLK=64
// LDS: dbuf{K 8KB + V 8KB} x2 = 32 KB  +  P 8 KB = 40 KB
template <int SPLIT>
__global__ __launch_bounds__(256) void attn_k(const __bf16* __restrict__ q,
                                              const __bf16* __restrict__ k,
                                              const __bf16* __restrict__ vt,
                                              float* __restrict__ Opart,
                                              float2* __restrict__ ml) {
  __shared__ __align__(16) char smem[40960];
  const int bid = blockIdx.x;
  const int p = bid % SPLIT;
  const int qb = (bid / SPLIT) & 31;
  const int b = bid / (SPLIT * 32);
  const int tid = threadIdx.x;
  const int lane = tid & 63;
  const int w = tid >> 6;
  const int l15 = lane & 15;
  const int g = lane >> 4;
  const size_t qkbase = (size_t)b * T_ * H_;
  const int qr0 = qb * 64 + w * 16;

  const __bf16* qp = q + qkbase + (size_t)(qr0 + l15) * H_ + g * 8;
  bf16x8 aq0 = *(const bf16x8*)qp;
  bf16x8 aq1 = *(const bf16x8*)(qp + 32);

  // staging addresses: K tile 64x128B (row=kv, chunk=h/8), V tile 64x128B (row=h, chunk=t/8)
  const int r0c = tid >> 3, x0c = (tid & 7) ^ (r0c & 7);
  const int r1c = (tid + 256) >> 3, x1c = (tid & 7) ^ (r1c & 7);
  const __bf16* ks0 = k + qkbase + (size_t)r0c * H_ + x0c * 8;
  const __bf16* ks1 = k + qkbase + (size_t)r1c * H_ + x1c * 8;
  const __bf16* vbase = vt + (size_t)b * 64 * T_;
  const __bf16* vs0 = vbase + (size_t)r0c * T_ + x0c * 8;
  const __bf16* vs1 = vbase + (size_t)r1c * T_ + x1c * 8;
  const int d0 = tid * 16, d1 = 4096 + tid * 16;

  auto stage = [&](int kvb, int bufo) {
    gl_lds16(ks0 + (size_t)kvb * H_, smem + bufo + d0);
    gl_lds16(ks1 + (size_t)kvb * H_, smem + bufo + d1);
    gl_lds16(vs0 + kvb, smem + bufo + 8192 + d0);
    gl_lds16(vs1 + kvb, smem + bufo + 8192 + d1);
  };

  f32x4 accO[4];
#pragma unroll
  for (int i = 0; i < 4; ++i) accO[i] = (f32x4)0.0f;
  float mrow[4] = {-1e30f, -1e30f, -1e30f, -1e30f};
  float lsum[4] = {0.f, 0.f, 0.f, 0.f};
  char* pb = smem + 32768 + w * 2048;

  const int len = (qb + SPLIT) / SPLIT;  // ceil((qb+1)/SPLIT)
  const int kb0 = p * len;
  int kbend = kb0 + len;
  if (kbend > qb + 1) kbend = qb + 1;

  if (kb0 < kbend) {
    stage(kb0 * 64, 0);
    __syncthreads();
    for (int kb = kb0; kb < kbend; ++kb) {
      const int bufo = ((kb - kb0) & 1) << 14;
      if (kb + 1 < kbend) stage((kb + 1) * 64, bufo ^ 16384);
      const int kvb = kb * 64;
      const char* kbuf = smem + bufo;
      const char* vbuf = smem + bufo + 8192;
      // S = Q K^T (scale pre-folded into q)
      f32x4 s[4];
#pragma unroll
      for (int ct = 0; ct < 4; ++ct) {
        const int row = ct * 16 + l15;
        bf16x8 b0 = *(const bf16x8*)(kbuf + row * 128 + ((g ^ (row & 7)) << 4));
        bf16x8 b1 = *(const bf16x8*)(kbuf + row * 128 + (((g + 4) ^ (row & 7)) << 4));
        f32x4 z = (f32x4)0.0f;
        z = __builtin_amdgcn_mfma_f32_16x16x32_bf16(aq0, b0, z, 0, 0, 0);
        z = __builtin_amdgcn_mfma_f32_16x16x32_bf16(aq1, b1, z, 0, 0, 0);
        s[ct] = z;
      }
      if (kb == qb) {  // causal mask on diagonal block
#pragma unroll
        for (int ct = 0; ct < 4; ++ct)
#pragma unroll
          for (int r = 0; r < 4; ++r)
            if (kvb + ct * 16 + l15 > qr0 + g * 4 + r) s[ct][r] = -1e30f;
      }
      // wave-parallel online softmax
      float al[4];
#pragma unroll
      for (int r = 0; r < 4; ++r) {
        float v = fmaxf(fmaxf(s[0][r], s[1][r]), fmaxf(s[2][r], s[3][r]));
        v = fmaxf(v, __shfl_xor(v, 1, 64));
        v = fmaxf(v, __shfl_xor(v, 2, 64));
        v = fmaxf(v, __shfl_xor(v, 4, 64));
        v = fmaxf(v, __shfl_xor(v, 8, 64));
        float m2 = fmaxf(mrow[r], v);
        al[r] = __expf(mrow[r] - m2);
        mrow[r] = m2;
      }
#pragma unroll
      for (int ct = 0; ct < 4; ++ct)
#pragma unroll
        for (int r = 0; r < 4; ++r) s[ct][r] = __expf(s[ct][r] - mrow[r]);
#pragma unroll
      for (int r = 0; r < 4; ++r) {
        lsum[r] = lsum[r] * al[r] + (s[0][r] + s[1][r]) + (s[2][r] + s[3][r]);
#pragma unroll
        for (int hct = 0; hct < 4; ++hct) accO[hct][r] *= al[r];
      }
      // P -> per-wave LDS tile (swizzled), read back as A-fragments
#pragma unroll
      for (int ct = 0; ct < 4; ++ct)
#pragma unroll
        for (int r = 0; r < 4; ++r) {
          int qrow = g * 4 + r;
          int off = ((qrow * 64 + ct * 16 + l15) * 2) ^ ((qrow & 7) << 4);
          *(__bf16*)(pb + off) = (__bf16)s[ct][r];
        }
#pragma unroll
      for (int ks = 0; ks < 2; ++ks) {
        int off = ((l15 * 64 + ks * 32 + g * 8) * 2) ^ ((l15 & 7) << 4);
        bf16x8 pa = *(const bf16x8*)(pb + off);
#pragma unroll
        for (int hct = 0; hct < 4; ++hct) {
          const int h = hct * 16 + l15;
          const int chunk = ks * 4 + g;
          bf16x8 bv = *(const bf16x8*)(vbuf + h * 128 + ((chunk ^ (h & 7)) << 4));
          accO[hct] = __builtin_amdgcn_mfma_f32_16x16x32_bf16(pa, bv, accO[hct], 0, 0, 0);
        }
      }
      __syncthreads();
    }
  }
  // reduce lsum across 16-lane group; write partials (unnormalized)
#pragma unroll
  for (int r = 0; r < 4; ++r) {
    float v = lsum[r];
    v += __shfl_xor(v, 1, 64);
    v += __shfl_xor(v, 2, 64);
    v += __shfl_xor(v, 4, 64);
    v += __shfl_xor(v, 8, 64);
    lsum[r] = v;
  }
  float* op = Opart + ((size_t)p * (B_ * T_) + (size_t)b * T_ + qr0) * H_;
#pragma unroll
  for (int hct = 0; hct < 4; ++hct)
#pragma unroll
    for (int r = 0; r < 4; ++r)
      op[(size_t)(g * 4 + r) * H_ + hct * 16 + l15] = accO[hct][r];
  if (l15 == 0) {
#pragma unroll
    for (int r = 0; r < 4; ++r)
      ml[(size_t)p * (B_ * T_) + (size_t)b * T_ + qr0 + g * 4 + r] =
          make_float2(mrow[r], lsum[r]);
  }
}

// ---------------- Kernel 3: combine split-KV partials ----------------
template <int SPLIT>
__global__ __launch_bounds__(256) void comb_k(const float* __restrict__ Opart,
                                              const float2* __restrict__ ml,
                                              float* __restrict__ out) {
  int gid = blockIdx.x * 256 + threadIdx.x;  // 262144 = 16384 rows x 16
  int row = gid >> 4;
  int h4 = (gid & 15) * 4;
  float m[SPLIT], l[SPLIT];
#pragma unroll
  for (int p = 0; p < SPLIT; ++p) {
    float2 t = ml[(size_t)p * (B_ * T_) + row];
    m[p] = t.x;
    l[p] = t.y;
  }
  float M = -1e30f;
#pragma unroll
  for (int p = 0; p < SPLIT; ++p) M = fmaxf(M, m[p]);
  float wp[SPLIT], wsum = 0.f;
#pragma unroll
  for (int p = 0; p < SPLIT; ++p) {
    wp[p] = __expf(m[p] - M);
    wsum += wp[p] * l[p];
  }
  float4 o = make_float4(0.f, 0.f, 0.f, 0.f);
#pragma unroll
  for (int p = 0; p < SPLIT; ++p) {
    float4 a = *(const float4*)(Opart + ((size_t)p * (B_ * T_) + row) * H_ + h4);
    o.x += wp[p] * a.x;
    o.y += wp[p] * a.y;
    o.z += wp[p] * a.z;
    o.w += wp[p] * a.w;
  }
  float inv = 1.0f / wsum;
  *(float4*)(out + (size_t)row * H_ + h4) =
      make_float4(o.x * inv, o.y * inv, o.z * inv, o.w * inv);
}

// ---------------- launcher ----------------
extern "C" void kernel_launch(void* const* d_in, const int* in_sizes, int n_in,
                              void* d_out, int out_size, void* d_ws, size_t ws_size,
                              hipStream_t stream) {
  const float* x  = (const float*)d_in[0];
  const float* Wq = (const float*)d_in[1];
  const float* Wk = (const float*)d_in[2];
  const float* Wv = (const float*)d_in[3];
  float* out = (float*)d_out;
  char* ws = (char*)d_ws;
  __bf16* Wt   = (__bf16*)ws;                  // 384 KiB
  __bf16* qb   = (__bf16*)(ws + 0x60000);      // 2 MiB
  __bf16* kb   = (__bf16*)(ws + 0x260000);     // 2 MiB
  __bf16* vtb  = (__bf16*)(ws + 0x460000);     // 2 MiB (vt[b][h][t])
  float*  Op   = (float*)(ws + 0x660000);      // 8 MiB (2 x 16384 x 64 f32)
  float2* mlb  = (float2*)(ws + 0xE60000);     // 256 KiB

  hipLaunchKernelGGL(prep_w_k, dim3(192), dim3(256), 0, stream, Wq, Wk, Wv, Wt);
  hipLaunchKernelGGL(qkv_k, dim3(512), dim3(256), 0, stream, x, Wt, qb, kb, vtb);
  hipLaunchKernelGGL(attn_k<2>, dim3(8 * 32 * 2), dim3(256), 0, stream, qb, kb, vtb, Op, mlb);
  hipLaunchKernelGGL(comb_k<2>, dim3(1024), dim3(256), 0, stream, Op, mlb, out);
}